// Round 1
// baseline (394.982 us; speedup 1.0000x reference)
//
#include <hip/hip_runtime.h>
#include <cstdint>
#include <cstddef>

#define H 1024
#define NB 8
#define S 2048
#define MROWS (NB*S)

using short8 = __attribute__((ext_vector_type(8))) short;
using f32x4  = __attribute__((ext_vector_type(4))) float;

__device__ __forceinline__ unsigned short f2bf(float f){
  union { float f; unsigned int u; } c; c.f = f;
  unsigned int u = c.u;
  return (unsigned short)((u + 0x7fffu + ((u >> 16) & 1u)) >> 16);
}

// ---------------- small prep kernels ----------------

__global__ void k_cvt_bf16(const float* __restrict__ src, unsigned short* __restrict__ dst, int n){
  int i = (blockIdx.x * blockDim.x + threadIdx.x) * 4;
  if (i >= n) return;
  float4 v = *reinterpret_cast<const float4*>(src + i);
  ushort4 o;
  o.x = f2bf(v.x); o.y = f2bf(v.y); o.z = f2bf(v.z); o.w = f2bf(v.w);
  *reinterpret_cast<ushort4*>(dst + i) = o;
}

// u[in] = sum_out W[out,in] * g[out]   (fp32-exact gate projection vectors)
__global__ void k_colproj(const float* __restrict__ Wa, const float* __restrict__ ga, float* __restrict__ ua,
                          const float* __restrict__ Wb, const float* __restrict__ gb, float* __restrict__ ub){
  const float* W = blockIdx.y ? Wb : Wa;
  const float* g = blockIdx.y ? gb : ga;
  float* u = blockIdx.y ? ub : ua;
  int in = blockIdx.x * 256 + threadIdx.x;
  float s = 0.f;
  for (int o = 0; o < H; ++o) s = fmaf(W[(size_t)o * H + in], g[o], s);
  u[in] = s;
}

// out[b*H + row] = sum_in Wc[row,in] * ctx[b,in]
__global__ __launch_bounds__(256) void k_ctxproj(const float* __restrict__ Wcq, const float* __restrict__ Wck,
    const float* __restrict__ ctx, float* __restrict__ outq, float* __restrict__ outk){
  __shared__ float cs[NB * H];
  const float* W = blockIdx.y ? Wck : Wcq;
  float* out = blockIdx.y ? outk : outq;
  const int t = threadIdx.x;
  for (int i = t; i < NB * H; i += 256) cs[i] = ctx[i];
  __syncthreads();
  const int wid = t >> 6, lane = t & 63;
  const int row = blockIdx.x * 4 + wid;
  float a[NB];
  #pragma unroll
  for (int b = 0; b < NB; ++b) a[b] = 0.f;
  for (int i0 = 0; i0 < H; i0 += 64){
    const float w = W[(size_t)row * H + i0 + lane];
    #pragma unroll
    for (int b = 0; b < NB; ++b) a[b] = fmaf(w, cs[b * H + i0 + lane], a[b]);
  }
  #pragma unroll
  for (int b = 0; b < NB; ++b){
    float v = a[b];
    #pragma unroll
    for (int off = 32; off > 0; off >>= 1) v += __shfl_xor(v, off);
    if (lane == 0) out[b * H + row] = v;
  }
}

__device__ float block_dot(const float* a, const float* b, float* red, int t){
  float s = 0.f;
  for (int i = t; i < H; i += 256) s = fmaf(a[i], b[i], s);
  red[t] = s;
  __syncthreads();
  for (int off = 128; off > 0; off >>= 1){
    if (t < off) red[t] += red[t + off];
    __syncthreads();
  }
  float r = red[0];
  __syncthreads();
  return r;
}

// scal[0]=bq.g_qh scal[1]=bk.g_kh scal[2+b]=ctx.g_qc scal[10+b]=ctx.g_kc
__global__ void k_scalars(const float* __restrict__ bq, const float* __restrict__ gqh,
                          const float* __restrict__ bk, const float* __restrict__ gkh,
                          const float* __restrict__ ctx, const float* __restrict__ gqc,
                          const float* __restrict__ gkc, float* __restrict__ scal){
  __shared__ float red[256];
  const int t = threadIdx.x;
  float v;
  v = block_dot(bq, gqh, red, t); if (t == 0) scal[0] = v;
  v = block_dot(bk, gkh, red, t); if (t == 0) scal[1] = v;
  for (int b = 0; b < NB; ++b){
    v = block_dot(ctx + b * H, gqc, red, t); if (t == 0) scal[2 + b] = v;
    v = block_dot(ctx + b * H, gkc, red, t); if (t == 0) scal[10 + b] = v;
  }
}

// hs f32 -> bf16, and fp32-exact gates per row
__global__ __launch_bounds__(256) void k_prepass(const float* __restrict__ hs,
    const float* __restrict__ u_q, const float* __restrict__ u_k, const float* __restrict__ scal,
    unsigned short* __restrict__ hsb, float* __restrict__ gq, float* __restrict__ gk){
  const int t = threadIdx.x, wid = t >> 6, lane = t & 63;
  const int row = blockIdx.x * 4 + wid;
  const float* hrow = hs + (size_t)row * H;
  unsigned short* orow = hsb + (size_t)row * H;
  float sq = 0.f, sk = 0.f;
  #pragma unroll
  for (int c = 0; c < 4; ++c){
    const int idx = (lane + c * 64) * 4;
    float4 v  = *reinterpret_cast<const float4*>(hrow + idx);
    float4 uq = *reinterpret_cast<const float4*>(u_q + idx);
    float4 uk = *reinterpret_cast<const float4*>(u_k + idx);
    ushort4 o; o.x = f2bf(v.x); o.y = f2bf(v.y); o.z = f2bf(v.z); o.w = f2bf(v.w);
    *reinterpret_cast<ushort4*>(orow + idx) = o;
    sq += v.x*uq.x + v.y*uq.y + v.z*uq.z + v.w*uq.w;
    sk += v.x*uk.x + v.y*uk.y + v.z*uk.z + v.w*uk.w;
  }
  #pragma unroll
  for (int off = 32; off > 0; off >>= 1){
    sq += __shfl_xor(sq, off);
    sk += __shfl_xor(sk, off);
  }
  if (lane == 0){
    const int b = row >> 11;
    gq[row] = 1.f / (1.f + __expf(-(sq + scal[0] + scal[2 + b])));
    gk[row] = 1.f / (1.f + __expf(-(sk + scal[1] + scal[10 + b])));
  }
}

// ---------------- main GEMM (bt form: C[i,j] = sum_k A[i,k]*B[j,k]) ----------------
// MODE 0: Qhat = gate-mix(hs@Wq^T+bq)      -> bf16 [16384,1024]
// MODE 1: Khat                              -> bf16
// MODE 2: V = hs@Wv^T+bv, stored TRANSPOSED -> bf16 Vt[b][h][s]
// MODE 3: scores = Qhat@Khat^T * scale      -> f32 d_out
// MODE 4: out = probs@Vt^T                  -> f32 d_out
template<int MODE>
__global__ __launch_bounds__(256, 2)
void k_gemm(const unsigned short* __restrict__ A, const unsigned short* __restrict__ B,
            int K, int ldA, int ldB, long long Abatch, long long Bbatch,
            const float* __restrict__ gate, const float* __restrict__ bias,
            const float* __restrict__ ctxv,
            unsigned short* __restrict__ outb, float* __restrict__ outf,
            long long outBatch, float scale)
{
  constexpr int SMEM_SHORTS = (MODE == 2) ? (128 * 129) : (128 * 64 * 2);
  __shared__ __align__(16) short smem[SMEM_SHORTS];
  short* As = smem;             // 128 rows x 64 k (bf16), XOR-swizzled 16B slots
  short* Bs = smem + 128 * 64;

  const int t = threadIdx.x;
  const int wid = t >> 6;
  const int lane = t & 63;
  const int bz = blockIdx.z;
  const unsigned short* Ab = A + (size_t)bz * (size_t)Abatch;
  const unsigned short* Bb = B + (size_t)bz * (size_t)Bbatch;
  const int row0 = blockIdx.x * 128;
  const int col0 = blockIdx.y * 128;
  const int wr = (wid >> 1) * 64;
  const int wc = (wid & 1) * 64;

  f32x4 acc[4][4] = {};

  const int nk = K >> 6;
  for (int kt = 0; kt < nk; ++kt){
    const int k0 = kt << 6;
    #pragma unroll
    for (int i = 0; i < 4; ++i){
      const int c   = (wid * 4 + i) * 64 + lane;   // 16B chunk id
      const int r   = c >> 3;                       // tile row
      const int sl  = c & 7;                        // 16B slot in row
      const int kcg = sl ^ (r & 7);                 // pre-swizzled global k-chunk
      const unsigned short* ga = Ab + (size_t)(row0 + r) * ldA + k0 + kcg * 8;
      const unsigned short* gb = Bb + (size_t)(col0 + r) * ldB + k0 + kcg * 8;
      __builtin_amdgcn_global_load_lds(
        (const __attribute__((address_space(1))) void*)ga,
        (__attribute__((address_space(3))) void*)((char*)As + (wid * 4 + i) * 1024),
        16, 0, 0);
      __builtin_amdgcn_global_load_lds(
        (const __attribute__((address_space(1))) void*)gb,
        (__attribute__((address_space(3))) void*)((char*)Bs + (wid * 4 + i) * 1024),
        16, 0, 0);
    }
    __syncthreads();
    #pragma unroll
    for (int kk = 0; kk < 2; ++kk){
      short8 af[4], bfr[4];
      #pragma unroll
      for (int m = 0; m < 4; ++m){
        const int ar = wr + m * 16 + (lane & 15);
        const int sl = ((kk * 4) + (lane >> 4)) ^ (ar & 7);
        af[m] = *reinterpret_cast<const short8*>((const char*)As + ar * 128 + sl * 16);
      }
      #pragma unroll
      for (int n = 0; n < 4; ++n){
        const int br = wc + n * 16 + (lane & 15);
        const int sl = ((kk * 4) + (lane >> 4)) ^ (br & 7);
        bfr[n] = *reinterpret_cast<const short8*>((const char*)Bs + br * 128 + sl * 16);
      }
      #pragma unroll
      for (int m = 0; m < 4; ++m)
        #pragma unroll
        for (int n = 0; n < 4; ++n)
          acc[m][n] = __builtin_amdgcn_mfma_f32_16x16x32_bf16(af[m], bfr[n], acc[m][n], 0, 0, 0);
    }
    __syncthreads();
  }

  // ---- epilogues ---- (C/D layout: col=lane&15, row=(lane>>4)*4+reg  [m89])
  if constexpr (MODE == 0 || MODE == 1){
    const int b = row0 >> 11;
    #pragma unroll
    for (int m = 0; m < 4; ++m)
      #pragma unroll
      for (int n = 0; n < 4; ++n)
        #pragma unroll
        for (int r = 0; r < 4; ++r){
          const int grow = row0 + wr + m * 16 + (lane >> 4) * 4 + r;
          const int gcol = col0 + wc + n * 16 + (lane & 15);
          const float g = gate[grow];
          const float q = acc[m][n][r] + bias[gcol];
          const float o = (1.f - g) * q + g * ctxv[b * H + gcol];
          outb[(size_t)grow * H + gcol] = f2bf(o);
        }
  } else if constexpr (MODE == 2){
    #pragma unroll
    for (int m = 0; m < 4; ++m)
      #pragma unroll
      for (int n = 0; n < 4; ++n)
        #pragma unroll
        for (int r = 0; r < 4; ++r){
          const int lr = wr + m * 16 + (lane >> 4) * 4 + r;
          const int lc = wc + n * 16 + (lane & 15);
          smem[lr * 129 + lc] = (short)f2bf(acc[m][n][r] + bias[col0 + lc]);
        }
    __syncthreads();
    const int bb = row0 >> 11;
    const int s0 = row0 & (S - 1);
    const int hl = t >> 1;
    const int sb = (t & 1) * 64;
    unsigned short* vout = outb + (size_t)bb * H * S + (size_t)(col0 + hl) * S + s0 + sb;
    #pragma unroll
    for (int i = 0; i < 64; i += 4){
      ushort4 o;
      o.x = (unsigned short)smem[(sb + i + 0) * 129 + hl];
      o.y = (unsigned short)smem[(sb + i + 1) * 129 + hl];
      o.z = (unsigned short)smem[(sb + i + 2) * 129 + hl];
      o.w = (unsigned short)smem[(sb + i + 3) * 129 + hl];
      *reinterpret_cast<ushort4*>(vout + i) = o;
    }
  } else if constexpr (MODE == 3){
    #pragma unroll
    for (int m = 0; m < 4; ++m)
      #pragma unroll
      for (int n = 0; n < 4; ++n)
        #pragma unroll
        for (int r = 0; r < 4; ++r){
          const int grow = row0 + wr + m * 16 + (lane >> 4) * 4 + r;
          const int gcol = col0 + wc + n * 16 + (lane & 15);
          outf[(size_t)bz * (size_t)outBatch + (size_t)grow * S + gcol] = acc[m][n][r] * scale;
        }
  } else {
    #pragma unroll
    for (int m = 0; m < 4; ++m)
      #pragma unroll
      for (int n = 0; n < 4; ++n)
        #pragma unroll
        for (int r = 0; r < 4; ++r){
          const int grow = row0 + wr + m * 16 + (lane >> 4) * 4 + r;
          const int gcol = col0 + wc + n * 16 + (lane & 15);
          outf[(size_t)bz * (size_t)outBatch + (size_t)grow * H + gcol] = acc[m][n][r];
        }
  }
}

// ---------------- softmax ----------------
__global__ __launch_bounds__(256) void k_softmax(const float* __restrict__ scores,
                                                 unsigned short* __restrict__ probs){
  const int row = blockIdx.x;
  const float* srow = scores + (size_t)row * S;
  unsigned short* prow = probs + (size_t)row * S;
  const int t = threadIdx.x, wid = t >> 6, lane = t & 63;
  __shared__ float red[8];
  float4 v0 = *reinterpret_cast<const float4*>(srow + t * 4);
  float4 v1 = *reinterpret_cast<const float4*>(srow + 1024 + t * 4);
  float m = fmaxf(fmaxf(fmaxf(v0.x, v0.y), fmaxf(v0.z, v0.w)),
                  fmaxf(fmaxf(v1.x, v1.y), fmaxf(v1.z, v1.w)));
  #pragma unroll
  for (int off = 32; off > 0; off >>= 1) m = fmaxf(m, __shfl_xor(m, off));
  if (lane == 0) red[wid] = m;
  __syncthreads();
  m = fmaxf(fmaxf(red[0], red[1]), fmaxf(red[2], red[3]));
  float4 e0, e1;
  e0.x = __expf(v0.x - m); e0.y = __expf(v0.y - m); e0.z = __expf(v0.z - m); e0.w = __expf(v0.w - m);
  e1.x = __expf(v1.x - m); e1.y = __expf(v1.y - m); e1.z = __expf(v1.z - m); e1.w = __expf(v1.w - m);
  float s = (e0.x + e0.y + e0.z + e0.w) + (e1.x + e1.y + e1.z + e1.w);
  #pragma unroll
  for (int off = 32; off > 0; off >>= 1) s += __shfl_xor(s, off);
  if (lane == 0) red[4 + wid] = s;
  __syncthreads();
  s = (red[4] + red[5]) + (red[6] + red[7]);
  const float inv = 1.f / s;
  ushort4 o;
  o.x = f2bf(e0.x * inv); o.y = f2bf(e0.y * inv); o.z = f2bf(e0.z * inv); o.w = f2bf(e0.w * inv);
  *reinterpret_cast<ushort4*>(prow + t * 4) = o;
  o.x = f2bf(e1.x * inv); o.y = f2bf(e1.y * inv); o.z = f2bf(e1.z * inv); o.w = f2bf(e1.w * inv);
  *reinterpret_cast<ushort4*>(prow + 1024 + t * 4) = o;
}

// ---------------- launch ----------------
extern "C" void kernel_launch(void* const* d_in, const int* in_sizes, int n_in,
                              void* d_out, int out_size, void* d_ws, size_t ws_size,
                              hipStream_t stream) {
  const float* hs  = (const float*)d_in[0];
  const float* ctx = (const float*)d_in[1];
  const float* Wq  = (const float*)d_in[2];
  const float* bq  = (const float*)d_in[3];
  const float* Wk  = (const float*)d_in[4];
  const float* bk  = (const float*)d_in[5];
  const float* Wv  = (const float*)d_in[6];
  const float* bv  = (const float*)d_in[7];
  const float* Wcq = (const float*)d_in[8];
  const float* Wck = (const float*)d_in[9];
  const float* gqh = (const float*)d_in[10];
  const float* gkh = (const float*)d_in[11];
  const float* gqc = (const float*)d_in[12];
  const float* gkc = (const float*)d_in[13];

  char* ws = (char*)d_ws;
  const size_t T = (size_t)MROWS * H * 2;       // 33,554,432 B per bf16 tensor
  unsigned short* hsb  = (unsigned short*)(ws);
  unsigned short* qhat = (unsigned short*)(ws + T);
  unsigned short* khat = (unsigned short*)(ws + 2 * T);
  unsigned short* vt   = (unsigned short*)(ws + 3 * T);
  unsigned short* wqb  = (unsigned short*)(ws + 4 * T);
  unsigned short* wkb  = (unsigned short*)(ws + 4 * T + 2097152);
  unsigned short* wvb  = (unsigned short*)(ws + 4 * T + 4194304);
  float* u_q  = (float*)(ws + 4 * T + 6291456);
  float* u_k  = u_q + H;
  float* ctxq = u_k + H;            // [NB][H]
  float* ctxk = ctxq + NB * H;
  float* gq   = ctxk + NB * H;      // [MROWS]
  float* gk   = gq + MROWS;
  float* scal = gk + MROWS;         // [18]
  unsigned short* probs = (unsigned short*)ws;   // reuse hsb+qhat (67.1 MB), dead by then

  float* out_attn   = (float*)d_out;                        // [NB,S,H]
  float* out_scores = out_attn + (size_t)MROWS * H;         // [NB,S,S]

  // prep
  k_cvt_bf16<<<1024, 256, 0, stream>>>(Wq, wqb, H * H);
  k_cvt_bf16<<<1024, 256, 0, stream>>>(Wk, wkb, H * H);
  k_cvt_bf16<<<1024, 256, 0, stream>>>(Wv, wvb, H * H);
  k_colproj<<<dim3(4, 2), 256, 0, stream>>>(Wq, gqh, u_q, Wk, gkh, u_k);
  k_ctxproj<<<dim3(256, 2), 256, 0, stream>>>(Wcq, Wck, ctx, ctxq, ctxk);
  k_scalars<<<1, 256, 0, stream>>>(bq, gqh, bk, gkh, ctx, gqc, gkc, scal);
  k_prepass<<<MROWS / 4, 256, 0, stream>>>(hs, u_q, u_k, scal, hsb, gq, gk);

  // QKV projections with gating epilogues (M=16384, N=1024, K=1024)
  k_gemm<0><<<dim3(128, 8, 1), 256, 0, stream>>>(hsb, wqb, 1024, 1024, 1024, 0, 0,
      gq, bq, ctxq, qhat, nullptr, 0, 1.f);
  k_gemm<1><<<dim3(128, 8, 1), 256, 0, stream>>>(hsb, wkb, 1024, 1024, 1024, 0, 0,
      gk, bk, ctxk, khat, nullptr, 0, 1.f);
  k_gemm<2><<<dim3(128, 8, 1), 256, 0, stream>>>(hsb, wvb, 1024, 1024, 1024, 0, 0,
      nullptr, bv, nullptr, vt, nullptr, 0, 1.f);

  // scores (per batch M=N=2048, K=1024), written f32 to d_out
  k_gemm<3><<<dim3(16, 16, 8), 256, 0, stream>>>(qhat, khat, 1024, 1024, 1024,
      (long long)S * H, (long long)S * H, nullptr, nullptr, nullptr,
      nullptr, out_scores, (long long)S * S, 0.03125f);

  // softmax -> probs bf16
  k_softmax<<<MROWS, 256, 0, stream>>>(out_scores, probs);

  // output = probs @ V (per batch M=2048, N=1024, K=2048; B operand = Vt)
  k_gemm<4><<<dim3(16, 8, 8), 256, 0, stream>>>(probs, vt, 2048, 2048, 2048,
      (long long)S * S, (long long)H * S, nullptr, nullptr, nullptr,
      nullptr, out_attn, (long long)S * H, 1.f);
}

// Round 2
// 357.022 us; speedup vs baseline: 1.1063x; 1.1063x over previous
//
#include <hip/hip_runtime.h>
#include <cstdint>
#include <cstddef>

#define H 1024
#define NB 8
#define S 2048
#define MROWS (NB*S)

using short8 = __attribute__((ext_vector_type(8))) short;
using f32x4  = __attribute__((ext_vector_type(4))) float;

__device__ __forceinline__ unsigned short f2bf(float f){
  union { float f; unsigned int u; } c; c.f = f;
  unsigned int u = c.u;
  return (unsigned short)((u + 0x7fffu + ((u >> 16) & 1u)) >> 16);
}

// ---------------- small prep kernels ----------------

__global__ void k_cvt3(const float* __restrict__ a, const float* __restrict__ b, const float* __restrict__ c,
                       unsigned short* __restrict__ oa, unsigned short* __restrict__ ob, unsigned short* __restrict__ oc){
  const float* src = blockIdx.y == 0 ? a : (blockIdx.y == 1 ? b : c);
  unsigned short* dst = blockIdx.y == 0 ? oa : (blockIdx.y == 1 ? ob : oc);
  int i = (blockIdx.x * 256 + threadIdx.x) * 4;
  float4 v = *reinterpret_cast<const float4*>(src + i);
  ushort4 o;
  o.x = f2bf(v.x); o.y = f2bf(v.y); o.z = f2bf(v.z); o.w = f2bf(v.w);
  *reinterpret_cast<ushort4*>(dst + i) = o;
}

// partial u[in] = sum over 128 o's of W[o,in]*g[o]; up layout [matrix2][chunk8][1024]
__global__ void k_colproj(const float* __restrict__ Wq_, const float* __restrict__ gq_,
                          const float* __restrict__ Wk_, const float* __restrict__ gk_,
                          float* __restrict__ up){
  const float* W = blockIdx.z ? Wk_ : Wq_;
  const float* g = blockIdx.z ? gk_ : gq_;
  const int in = blockIdx.x * 256 + threadIdx.x;
  const int o0 = blockIdx.y * 128;
  float s = 0.f;
  for (int o = 0; o < 128; ++o) s = fmaf(W[(size_t)(o0 + o) * H + in], g[o0 + o], s);
  up[(blockIdx.z * 8 + blockIdx.y) * 1024 + in] = s;
}

__global__ void k_ucombine(const float* __restrict__ up, float* __restrict__ uq, float* __restrict__ uk){
  int i = blockIdx.x * 256 + threadIdx.x;  // 0..2047
  int m = i >> 10, j = i & 1023;
  float s = 0.f;
  #pragma unroll
  for (int c = 0; c < 8; ++c) s += up[(m * 8 + c) * 1024 + j];
  (m ? uk : uq)[j] = s;
}

// out[b*H + row] = sum_in Wc[row,in] * ctx[b,in]
__global__ __launch_bounds__(256) void k_ctxproj(const float* __restrict__ Wcq, const float* __restrict__ Wck,
    const float* __restrict__ ctx, float* __restrict__ outq, float* __restrict__ outk){
  __shared__ float cs[NB * H];
  const float* W = blockIdx.y ? Wck : Wcq;
  float* out = blockIdx.y ? outk : outq;
  const int t = threadIdx.x;
  for (int i = t; i < NB * H; i += 256) cs[i] = ctx[i];
  __syncthreads();
  const int wid = t >> 6, lane = t & 63;
  const int row = blockIdx.x * 4 + wid;
  float a[NB];
  #pragma unroll
  for (int b = 0; b < NB; ++b) a[b] = 0.f;
  for (int i0 = 0; i0 < H; i0 += 64){
    const float w = W[(size_t)row * H + i0 + lane];
    #pragma unroll
    for (int b = 0; b < NB; ++b) a[b] = fmaf(w, cs[b * H + i0 + lane], a[b]);
  }
  #pragma unroll
  for (int b = 0; b < NB; ++b){
    float v = a[b];
    #pragma unroll
    for (int off = 32; off > 0; off >>= 1) v += __shfl_xor(v, off);
    if (lane == 0) out[b * H + row] = v;
  }
}

__device__ float block_dot(const float* a, const float* b, float* red, int t){
  float s = 0.f;
  for (int i = t; i < H; i += 256) s = fmaf(a[i], b[i], s);
  red[t] = s;
  __syncthreads();
  for (int off = 128; off > 0; off >>= 1){
    if (t < off) red[t] += red[t + off];
    __syncthreads();
  }
  float r = red[0];
  __syncthreads();
  return r;
}

// scal[0]=bq.g_qh scal[1]=bk.g_kh scal[2+b]=ctx.g_qc scal[10+b]=ctx.g_kc
__global__ void k_scalars(const float* __restrict__ bq, const float* __restrict__ gqh,
                          const float* __restrict__ bk, const float* __restrict__ gkh,
                          const float* __restrict__ ctx, const float* __restrict__ gqc,
                          const float* __restrict__ gkc, float* __restrict__ scal){
  __shared__ float red[256];
  const int t = threadIdx.x;
  float v;
  v = block_dot(bq, gqh, red, t); if (t == 0) scal[0] = v;
  v = block_dot(bk, gkh, red, t); if (t == 0) scal[1] = v;
  for (int b = 0; b < NB; ++b){
    v = block_dot(ctx + b * H, gqc, red, t); if (t == 0) scal[2 + b] = v;
    v = block_dot(ctx + b * H, gkc, red, t); if (t == 0) scal[10 + b] = v;
  }
}

// hs f32 -> bf16, and fp32-exact gates per row
__global__ __launch_bounds__(256) void k_prepass(const float* __restrict__ hs,
    const float* __restrict__ u_q, const float* __restrict__ u_k, const float* __restrict__ scal,
    unsigned short* __restrict__ hsb, float* __restrict__ gq, float* __restrict__ gk){
  const int t = threadIdx.x, wid = t >> 6, lane = t & 63;
  const int row = blockIdx.x * 4 + wid;
  const float* hrow = hs + (size_t)row * H;
  unsigned short* orow = hsb + (size_t)row * H;
  float sq = 0.f, sk = 0.f;
  #pragma unroll
  for (int c = 0; c < 4; ++c){
    const int idx = (lane + c * 64) * 4;
    float4 v  = *reinterpret_cast<const float4*>(hrow + idx);
    float4 uq = *reinterpret_cast<const float4*>(u_q + idx);
    float4 uk = *reinterpret_cast<const float4*>(u_k + idx);
    ushort4 o; o.x = f2bf(v.x); o.y = f2bf(v.y); o.z = f2bf(v.z); o.w = f2bf(v.w);
    *reinterpret_cast<ushort4*>(orow + idx) = o;
    sq += v.x*uq.x + v.y*uq.y + v.z*uq.z + v.w*uq.w;
    sk += v.x*uk.x + v.y*uk.y + v.z*uk.z + v.w*uk.w;
  }
  #pragma unroll
  for (int off = 32; off > 0; off >>= 1){
    sq += __shfl_xor(sq, off);
    sk += __shfl_xor(sk, off);
  }
  if (lane == 0){
    const int b = row >> 11;
    gq[row] = 1.f / (1.f + __expf(-(sq + scal[0] + scal[2 + b])));
    gk[row] = 1.f / (1.f + __expf(-(sk + scal[1] + scal[10 + b])));
  }
}

// ---------------- 256x256 8-phase GEMM (bt form: C[i,j] = sum_k A[i,k]*B[j,k]) ----------------
// MODE 0: Qhat = gate-mix(hs@Wq^T+bq)       -> bf16 [16384,1024]
// MODE 1: Khat                               -> bf16
// MODE 2: V = hs@Wv^T+bv, stored TRANSPOSED  -> bf16 Vt[b][h][s]
// MODE 3: scores = Qhat@Khat^T * scale       -> f32 d_out
// MODE 4: out = probs@Vt^T                   -> f32 d_out

#define STG(bufi, opi, halfi, koff, P0, P1) \
  { __builtin_amdgcn_global_load_lds((const __attribute__((address_space(1))) void*)(P0 + (koff)), \
      (__attribute__((address_space(3))) void*)((char*)(&lds[bufi][opi][halfi][0]) + (wid*2+0)*1024), 16, 0, 0); \
    __builtin_amdgcn_global_load_lds((const __attribute__((address_space(1))) void*)(P1 + (koff)), \
      (__attribute__((address_space(3))) void*)((char*)(&lds[bufi][opi][halfi][0]) + (wid*2+1)*1024), 16, 0, 0); }
#define STG_A(bufi, halfi, koff) STG(bufi, 0, halfi, koff, sA0, sA1)
#define STG_B(bufi, halfi, koff) STG(bufi, 1, halfi, koff, sB0, sB1)

#define DS_A(bufi, ks, mh) \
  { _Pragma("unroll") for (int m_ = 0; m_ < 4; ++m_){ \
      const int ar_ = wr*128 + ((mh)*4 + m_)*16 + (lane & 15); \
      const int sl_ = (lane >> 4) ^ ((ar_ >> 1) & 3); \
      af[m_] = *reinterpret_cast<const short8*>(&lds[bufi][0][ks][ar_*32 + sl_*8]); } }
#define DS_B(bufi, ks) \
  { _Pragma("unroll") for (int n_ = 0; n_ < 4; ++n_){ \
      const int br_ = wc*64 + n_*16 + (lane & 15); \
      const int sl_ = (lane >> 4) ^ ((br_ >> 1) & 3); \
      bf[n_] = *reinterpret_cast<const short8*>(&lds[bufi][1][ks][br_*32 + sl_*8]); } }
#define MFMA16(mh) \
  { __builtin_amdgcn_s_setprio(1); \
    _Pragma("unroll") for (int m_ = 0; m_ < 4; ++m_) \
      _Pragma("unroll") for (int n_ = 0; n_ < 4; ++n_) \
        acc[(mh)*4 + m_][n_] = __builtin_amdgcn_mfma_f32_16x16x32_bf16(af[m_], bf[n_], acc[(mh)*4 + m_][n_], 0, 0, 0); \
    __builtin_amdgcn_s_setprio(0); }
#define VM4() asm volatile("s_waitcnt vmcnt(4)" ::: "memory");
#define VM0() asm volatile("s_waitcnt vmcnt(0)" ::: "memory");
#define BAR() { asm volatile("" ::: "memory"); __builtin_amdgcn_s_barrier(); asm volatile("" ::: "memory"); }

template<int MODE>
__global__ __launch_bounds__(512, 2)
void k_gemm(const unsigned short* __restrict__ A, const unsigned short* __restrict__ B,
            int K, int ldA, int ldB, long long Abatch, long long Bbatch,
            const float* __restrict__ gate, const float* __restrict__ bias,
            const float* __restrict__ ctxv,
            unsigned short* __restrict__ outb, float* __restrict__ outf,
            long long outBatch, float scale)
{
  // [buf][op A=0,B=1][khalf][256 rows * 4 slots * 8 bf16] = 128 KiB total
  __shared__ __align__(16) short lds[2][2][2][8192];

  const int t = threadIdx.x;
  const int wid = t >> 6, lane = t & 63;
  const int wr = wid >> 2, wc = wid & 3;      // 2 x 4 wave grid
  const int bz = blockIdx.z;
  const unsigned short* Ab = A + (size_t)bz * (size_t)Abatch;
  const unsigned short* Bb = B + (size_t)bz * (size_t)Bbatch;
  const int row0 = blockIdx.x * 256;
  const int col0 = blockIdx.y * 256;

  // staging constants: thread's 2 chunks within a 16KB half (256 rows x 4 slots of 16B)
  const int c0 = (wid*2 + 0)*64 + lane;
  const int c1 = (wid*2 + 1)*64 + lane;
  const int r0s = c0 >> 2, r1s = c1 >> 2;
  const int kc0 = (c0 & 3) ^ ((r0s >> 1) & 3);   // pre-swizzled global k-chunk (involution)
  const int kc1 = (c1 & 3) ^ ((r1s >> 1) & 3);
  const unsigned short* sA0 = Ab + (size_t)(row0 + r0s) * (size_t)ldA + kc0*8;
  const unsigned short* sA1 = Ab + (size_t)(row0 + r1s) * (size_t)ldA + kc1*8;
  const unsigned short* sB0 = Bb + (size_t)(col0 + r0s) * (size_t)ldB + kc0*8;
  const unsigned short* sB1 = Bb + (size_t)(col0 + r1s) * (size_t)ldB + kc1*8;

  f32x4 acc[8][4] = {};
  short8 af[4], bf[4];

  // prologue: stage tile 0 into buf0 (4 halves), drain, barrier
  STG_A(0, 0, 0); STG_B(0, 0, 0); STG_A(0, 1, 32); STG_B(0, 1, 32);
  VM0(); BAR();

  const int niter = K >> 7;       // 2 K-tiles (of 64) per iteration
  for (int it = 0; it < niter; ++it){
    const int t1k = (it*2 + 1) << 6;
    const int t2k = (it*2 + 2) << 6;
    const bool more = (it + 1 < niter);
    // p1: compute buf0 (ks0, mh0); stage tile t1 A-half0 -> buf1
    DS_A(0, 0, 0); DS_B(0, 0); STG_A(1, 0, t1k); MFMA16(0); BAR();
    // p2: (ks0, mh1); stage t1 B-half0
    DS_A(0, 0, 1); STG_B(1, 0, t1k); MFMA16(1); VM4(); BAR();
    // p3: (ks1, mh0); stage t1 A-half1
    DS_A(0, 1, 0); DS_B(0, 1); STG_A(1, 1, t1k + 32); MFMA16(0); BAR();
    // p4: (ks1, mh1); stage t1 B-half1
    DS_A(0, 1, 1); STG_B(1, 1, t1k + 32); MFMA16(1);
    if (more) { VM4(); } else { VM0(); }
    BAR();
    // p5: compute buf1 (ks0, mh0); stage tile t0+2 A-half0 -> buf0
    DS_A(1, 0, 0); DS_B(1, 0); if (more) STG_A(0, 0, t2k); MFMA16(0); BAR();
    // p6
    DS_A(1, 0, 1); if (more) { STG_B(0, 0, t2k); } MFMA16(1); if (more) VM4(); BAR();
    // p7
    DS_A(1, 1, 0); DS_B(1, 1); if (more) STG_A(0, 1, t2k + 32); MFMA16(0); BAR();
    // p8
    DS_A(1, 1, 1); if (more) { STG_B(0, 1, t2k + 32); } MFMA16(1); if (more) VM4(); BAR();
  }

  // ---- epilogues ---- (C/D layout m89: col=lane&15, row=(lane>>4)*4+reg)
  if constexpr (MODE == 0 || MODE == 1){
    const int b = row0 >> 11;
    #pragma unroll
    for (int mi = 0; mi < 8; ++mi)
      #pragma unroll
      for (int n = 0; n < 4; ++n)
        #pragma unroll
        for (int r = 0; r < 4; ++r){
          const int grow = row0 + wr*128 + mi*16 + (lane >> 4)*4 + r;
          const int gcol = col0 + wc*64 + n*16 + (lane & 15);
          const float g = gate[grow];
          const float q = acc[mi][n][r] + bias[gcol];
          outb[(size_t)grow * H + gcol] = f2bf((1.f - g) * q + g * ctxv[b * H + gcol]);
        }
  } else if constexpr (MODE == 2){
    short* tp = (short*)lds;   // reuse as [128][129] scratch
    const int bb = row0 >> 11;
    const int s0 = row0 & (S - 1);
    #pragma unroll
    for (int ci = 0; ci < 2; ++ci)
      #pragma unroll
      for (int cj = 0; cj < 2; ++cj){
        __syncthreads();
        if (wr == ci && (wc >> 1) == cj){
          const int lc0 = (wc & 1) * 64;
          #pragma unroll
          for (int mi = 0; mi < 8; ++mi)
            #pragma unroll
            for (int n = 0; n < 4; ++n)
              #pragma unroll
              for (int r = 0; r < 4; ++r){
                const int lr = mi*16 + (lane >> 4)*4 + r;
                const int lc = lc0 + n*16 + (lane & 15);
                tp[lr*129 + lc] = (short)f2bf(acc[mi][n][r] + bias[col0 + cj*128 + lc]);
              }
        }
        __syncthreads();
        const int hl = t >> 2;           // 0..127 local col (h)
        const int sb = (t & 3) * 32;     // local row (s) start
        unsigned short* vout = outb + (size_t)bb * H * S + (size_t)(col0 + cj*128 + hl) * S
                                    + (size_t)(s0 + ci*128 + sb);
        #pragma unroll
        for (int i2 = 0; i2 < 32; i2 += 4){
          ushort4 o;
          o.x = (unsigned short)tp[(sb + i2 + 0)*129 + hl];
          o.y = (unsigned short)tp[(sb + i2 + 1)*129 + hl];
          o.z = (unsigned short)tp[(sb + i2 + 2)*129 + hl];
          o.w = (unsigned short)tp[(sb + i2 + 3)*129 + hl];
          *reinterpret_cast<ushort4*>(vout + i2) = o;
        }
      }
  } else if constexpr (MODE == 3){
    #pragma unroll
    for (int mi = 0; mi < 8; ++mi)
      #pragma unroll
      for (int n = 0; n < 4; ++n)
        #pragma unroll
        for (int r = 0; r < 4; ++r){
          const int grow = row0 + wr*128 + mi*16 + (lane >> 4)*4 + r;
          const int gcol = col0 + wc*64 + n*16 + (lane & 15);
          outf[(size_t)bz * (size_t)outBatch + (size_t)grow * S + gcol] = acc[mi][n][r] * scale;
        }
  } else {
    #pragma unroll
    for (int mi = 0; mi < 8; ++mi)
      #pragma unroll
      for (int n = 0; n < 4; ++n)
        #pragma unroll
        for (int r = 0; r < 4; ++r){
          const int grow = row0 + wr*128 + mi*16 + (lane >> 4)*4 + r;
          const int gcol = col0 + wc*64 + n*16 + (lane & 15);
          outf[(size_t)bz * (size_t)outBatch + (size_t)grow * H + gcol] = acc[mi][n][r];
        }
  }
}

// ---------------- softmax ----------------
__global__ __launch_bounds__(256) void k_softmax(const float* __restrict__ scores,
                                                 unsigned short* __restrict__ probs){
  const int row = blockIdx.x;
  const float* srow = scores + (size_t)row * S;
  unsigned short* prow = probs + (size_t)row * S;
  const int t = threadIdx.x, wid = t >> 6, lane = t & 63;
  __shared__ float red[8];
  float4 v0 = *reinterpret_cast<const float4*>(srow + t * 4);
  float4 v1 = *reinterpret_cast<const float4*>(srow + 1024 + t * 4);
  float m = fmaxf(fmaxf(fmaxf(v0.x, v0.y), fmaxf(v0.z, v0.w)),
                  fmaxf(fmaxf(v1.x, v1.y), fmaxf(v1.z, v1.w)));
  #pragma unroll
  for (int off = 32; off > 0; off >>= 1) m = fmaxf(m, __shfl_xor(m, off));
  if (lane == 0) red[wid] = m;
  __syncthreads();
  m = fmaxf(fmaxf(red[0], red[1]), fmaxf(red[2], red[3]));
  float4 e0, e1;
  e0.x = __expf(v0.x - m); e0.y = __expf(v0.y - m); e0.z = __expf(v0.z - m); e0.w = __expf(v0.w - m);
  e1.x = __expf(v1.x - m); e1.y = __expf(v1.y - m); e1.z = __expf(v1.z - m); e1.w = __expf(v1.w - m);
  float s = (e0.x + e0.y + e0.z + e0.w) + (e1.x + e1.y + e1.z + e1.w);
  #pragma unroll
  for (int off = 32; off > 0; off >>= 1) s += __shfl_xor(s, off);
  if (lane == 0) red[4 + wid] = s;
  __syncthreads();
  s = (red[4] + red[5]) + (red[6] + red[7]);
  const float inv = 1.f / s;
  ushort4 o;
  o.x = f2bf(e0.x * inv); o.y = f2bf(e0.y * inv); o.z = f2bf(e0.z * inv); o.w = f2bf(e0.w * inv);
  *reinterpret_cast<ushort4*>(prow + t * 4) = o;
  o.x = f2bf(e1.x * inv); o.y = f2bf(e1.y * inv); o.z = f2bf(e1.z * inv); o.w = f2bf(e1.w * inv);
  *reinterpret_cast<ushort4*>(prow + 1024 + t * 4) = o;
}

// ---------------- launch ----------------
extern "C" void kernel_launch(void* const* d_in, const int* in_sizes, int n_in,
                              void* d_out, int out_size, void* d_ws, size_t ws_size,
                              hipStream_t stream) {
  const float* hs  = (const float*)d_in[0];
  const float* ctx = (const float*)d_in[1];
  const float* Wq  = (const float*)d_in[2];
  const float* bq  = (const float*)d_in[3];
  const float* Wk  = (const float*)d_in[4];
  const float* bk  = (const float*)d_in[5];
  const float* Wv  = (const float*)d_in[6];
  const float* bv  = (const float*)d_in[7];
  const float* Wcq = (const float*)d_in[8];
  const float* Wck = (const float*)d_in[9];
  const float* gqh = (const float*)d_in[10];
  const float* gkh = (const float*)d_in[11];
  const float* gqc = (const float*)d_in[12];
  const float* gkc = (const float*)d_in[13];

  char* ws = (char*)d_ws;
  const size_t T = (size_t)MROWS * H * 2;       // 33,554,432 B per bf16 tensor
  unsigned short* hsb  = (unsigned short*)(ws);
  unsigned short* qhat = (unsigned short*)(ws + T);
  unsigned short* khat = (unsigned short*)(ws + 2 * T);
  unsigned short* vt   = (unsigned short*)(ws + 3 * T);
  unsigned short* wqb  = (unsigned short*)(ws + 4 * T);
  unsigned short* wkb  = (unsigned short*)(ws + 4 * T + 2097152);
  unsigned short* wvb  = (unsigned short*)(ws + 4 * T + 4194304);
  float* fb    = (float*)(ws + 4 * T + 6291456);
  float* u_q   = fb;                 // [1024]
  float* u_k   = fb + 1024;
  float* ctxq  = fb + 2048;          // [NB][H]
  float* ctxk  = fb + 10240;
  float* gq    = fb + 18432;         // [MROWS]
  float* gk    = fb + 34816;
  float* scal  = fb + 51200;         // [18]
  float* u_part= fb + 51232;         // [2][8][1024]
  unsigned short* probs = (unsigned short*)ws;   // reuse hsb+qhat region, dead by then

  float* out_attn   = (float*)d_out;                        // [NB,S,H]
  float* out_scores = out_attn + (size_t)MROWS * H;         // [NB,S,S]

  // prep
  k_cvt3<<<dim3(1024, 3), 256, 0, stream>>>(Wq, Wk, Wv, wqb, wkb, wvb);
  k_colproj<<<dim3(4, 8, 2), 256, 0, stream>>>(Wq, gqh, Wk, gkh, u_part);
  k_ucombine<<<8, 256, 0, stream>>>(u_part, u_q, u_k);
  k_ctxproj<<<dim3(256, 2), 256, 0, stream>>>(Wcq, Wck, ctx, ctxq, ctxk);
  k_scalars<<<1, 256, 0, stream>>>(bq, gqh, bk, gkh, ctx, gqc, gkc, scal);
  k_prepass<<<MROWS / 4, 256, 0, stream>>>(hs, u_q, u_k, scal, hsb, gq, gk);

  // QKV projections with gating epilogues (M=16384, N=1024, K=1024) - 256 blocks each
  k_gemm<0><<<dim3(64, 4, 1), 512, 0, stream>>>(hsb, wqb, 1024, 1024, 1024, 0, 0,
      gq, bq, ctxq, qhat, nullptr, 0, 1.f);
  k_gemm<1><<<dim3(64, 4, 1), 512, 0, stream>>>(hsb, wkb, 1024, 1024, 1024, 0, 0,
      gk, bk, ctxk, khat, nullptr, 0, 1.f);
  k_gemm<2><<<dim3(64, 4, 1), 512, 0, stream>>>(hsb, wvb, 1024, 1024, 1024, 0, 0,
      nullptr, bv, nullptr, vt, nullptr, 0, 1.f);

  // scores (per batch M=N=2048, K=1024), written f32 to d_out - 512 blocks
  k_gemm<3><<<dim3(8, 8, 8), 512, 0, stream>>>(qhat, khat, 1024, 1024, 1024,
      (long long)S * H, (long long)S * H, nullptr, nullptr, nullptr,
      nullptr, out_scores, (long long)S * S, 0.03125f);

  // softmax -> probs bf16
  k_softmax<<<MROWS, 256, 0, stream>>>(out_scores, probs);

  // output = probs @ V (per batch M=2048, N=1024, K=2048; B operand = Vt) - 256 blocks
  k_gemm<4><<<dim3(8, 4, 8), 512, 0, stream>>>(probs, vt, 2048, 2048, 2048,
      (long long)S * S, (long long)H * S, nullptr, nullptr, nullptr,
      nullptr, out_attn, (long long)S * H, 1.f);
}